// Round 15
// baseline (6914.681 us; speedup 1.0000x reference)
//
#include <hip/hip_runtime.h>
#include <hip/hip_bf16.h>
#include <cstdint>

// Problem constants
constexpr int kT = 128;    // sequence length
constexpr int kB = 256;    // batch
constexpr int kE = 512;    // embed dim
constexpr int kH = 1024;   // hidden
constexpr int kV = 348;    // vocab
constexpr int kNG = 3072;  // 3*H gate width
constexpr int NB = 104;    // 96 layer blocks (512 thr, full batch) + 8 E blocks

constexpr float kScale = 32.f;        // fp8 storage scale (avoids e4m3 subnormal floor)
constexpr float kInvSS = 1.f / 1024.f; // 1/(kScale*kScale) applied to accumulators

typedef float f4v __attribute__((ext_vector_type(4)));   // MFMA accumulator
typedef unsigned short u16;
typedef unsigned char u8;

// float -> fp8 e4m3 (OCP) via HW packed convert; low byte of the pair
__device__ __forceinline__ u8 f2e4m3(float x) {
  int p = __builtin_amdgcn_cvt_pk_fp8_f32(x, x, 0, false);
  return (u8)(p & 0xff);
}

// device-coherent (cross-XCD) accessors: bypass L1/L2, hit MALL coherent point
__device__ __forceinline__ uint64_t ldv_u64(const void* p) {
  return __hip_atomic_load((const uint64_t*)p, __ATOMIC_RELAXED, __HIP_MEMORY_SCOPE_AGENT);
}
__device__ __forceinline__ void stv_u8(u8* p, u8 v) {
  __hip_atomic_store(p, v, __ATOMIC_RELAXED, __HIP_MEMORY_SCOPE_AGENT);
}

// gate-major n = gate*H + j  ->  interleaved col = 48*(j/16) + 16*gate + (j%16)
__device__ __forceinline__ int permn(int n) {
  int gate = n >> 10, j = n & 1023;
  return ((j >> 4) * 48) + gate * 16 + (j & 15);
}

struct Params {
  const int* target; const int* bosp; const float* b_out;
  const u8 *w1i, *w1h, *w2i, *w2h, *w3i, *w3h, *wout, *embb;  // fp8 x32
  const float *bi1, *bh1, *bi2, *bh2, *bi3, *bh3;
  float *h1f, *h2f, *h3f;       // [2][B][H] fp32 state (block-local, cached)
  u8    *h1b, *h2b, *h3b;       // [2][B][H] fp8 x32 state (cross-block, MALL)
  float *lp;                    // [B] output accumulator (= d_out)
  unsigned *acnt; unsigned *gflag;
};

// LDS: 128B row stride, XOR-swizzled at 8B granularity (validated R2/R3).
// A = FULL 256-row batch tile now (512-thread blocks, 2 waves/SIMD).
union SMem {
  struct { u8 A[256 * 128]; u8 B[96 * 128]; } mm;   // 32KB + 12KB
  float logits[32 * 400];                           // 51.2KB (E: 2 tiles/block)
};

// ---- RAW workgroup barrier: waits LDS ops only, never drains vmcnt (R10-validated) ----
#define BAR_LDS() asm volatile("s_waitcnt lgkmcnt(0)\n\ts_barrier" ::: "memory")

// ---- grid barrier (R13 form): relaxed flag ops; full drain once per step ----
__device__ __forceinline__ void gbar(unsigned* acnt, unsigned* gflag, unsigned s) {
  asm volatile("s_waitcnt vmcnt(0)" ::: "memory");
  __syncthreads();
  if (threadIdx.x == 0) {
    const unsigned g = blockIdx.x & 31u;
    __hip_atomic_fetch_add(&acnt[g * 16], 1u, __ATOMIC_RELAXED, __HIP_MEMORY_SCOPE_AGENT);
    if (blockIdx.x == 0) {
      for (;;) {
        unsigned sum = 0;
#pragma unroll
        for (int i = 0; i < 32; ++i)
          sum += __hip_atomic_load(&acnt[i * 16], __ATOMIC_RELAXED, __HIP_MEMORY_SCOPE_AGENT);
        if (sum >= (unsigned)NB * (s + 1u)) break;
        __builtin_amdgcn_s_sleep(4);
      }
#pragma unroll
      for (int i = 0; i < 32; ++i)
        __hip_atomic_store(&gflag[i * 16], s + 1u, __ATOMIC_RELAXED, __HIP_MEMORY_SCOPE_AGENT);
    } else {
      while (__hip_atomic_load(&gflag[g * 16], __ATOMIC_RELAXED, __HIP_MEMORY_SCOPE_AGENT) <= s)
        __builtin_amdgcn_s_sleep(8);
    }
    asm volatile("" ::: "memory");
  }
  __syncthreads();
}

// ---- staging/compute macros, 512-thread versions: named register sets only
// ---- (round-4 lesson), FIFO-ordered per-tile issue (round-8 lesson).
#define LOAD_A(dst, k0)                                                      \
  _Pragma("unroll")                                                          \
  for (int p = 0; p < 4; ++p) {                                              \
    int id = p * 512 + t, r = id >> 3, c = id & 7;                           \
    if (EMB) {                                                               \
      int tok = (u == 0) ? bos : target[r * kT + (u - 1)];                   \
      uint4 v = *(const uint4*)&Asrc[(size_t)tok * K + (k0) + c * 16];       \
      dst[p][0] = ((uint64_t)v.y << 32) | v.x;                               \
      dst[p][1] = ((uint64_t)v.w << 32) | v.z;                               \
    } else {                                                                 \
      const u8* srcp = Asrc + (size_t)r * kH + (k0) + c * 16;                \
      dst[p][0] = ldv_u64(srcp); dst[p][1] = ldv_u64(srcp + 8);              \
    }                                                                        \
  }

#define LOAD_B(dst, k0)                                                      \
  _Pragma("unroll")                                                          \
  for (int p = 0; p < 2; ++p) {                                              \
    int id = p * 512 + t;                                                    \
    if (id < 768) {                                                          \
      int r = id >> 3, c = id & 7;                                           \
      dst[p] = *(const uint4*)&W[(size_t)(n0 + r) * K + (k0) + c * 16];      \
    }                                                                        \
  }

#define WR_AB(srcA, srcB)                                                    \
  _Pragma("unroll")                                                          \
  for (int p = 0; p < 4; ++p) {                                              \
    int id = p * 512 + t, r = id >> 3, c = id & 7;                           \
    const int u0 = c * 2, rx = r & 15;                                       \
    u8* base = &sm.mm.A[r * 128];                                            \
    *(uint64_t*)(base + 8 * (u0 ^ rx)) = srcA[p][0];                         \
    *(uint64_t*)(base + 8 * ((u0 + 1) ^ rx)) = srcA[p][1];                   \
  }                                                                          \
  _Pragma("unroll")                                                          \
  for (int p = 0; p < 2; ++p) {                                              \
    int id = p * 512 + t;                                                    \
    if (id < 768) {                                                          \
      int r = id >> 3, c = id & 7;                                           \
      const int u0 = c * 2, rx = r & 15;                                     \
      u8* base = &sm.mm.B[r * 128];                                          \
      *(uint64_t*)(base + 8 * (u0 ^ rx)) = (uint64_t)srcB[p].x | ((uint64_t)srcB[p].y << 32); \
      *(uint64_t*)(base + 8 * ((u0 + 1) ^ rx)) = (uint64_t)srcB[p].z | ((uint64_t)srcB[p].w << 32); \
    }                                                                        \
  }

#define MFMA_TILE()                                                          \
  _Pragma("unroll")                                                          \
  for (int kk = 0; kk < 128; kk += 32) {                                     \
    const int swz = 8 * (((kk >> 3) + q) ^ li);                              \
    long a[4], bb[3];                                                        \
    _Pragma("unroll")                                                        \
    for (int m2 = 0; m2 < 4; ++m2)                                           \
      a[m2] = *(const long*)&sm.mm.A[(64 * wm + 16 * m2 + li) * 128 + swz];  \
    _Pragma("unroll")                                                        \
    for (int g = 0; g < 3; ++g)                                              \
      bb[g] = *(const long*)&sm.mm.B[(48 * wg + 16 * g + li) * 128 + swz];   \
    _Pragma("unroll")                                                        \
    for (int m2 = 0; m2 < 4; ++m2) {                                         \
      aR[m2] = __builtin_amdgcn_mfma_f32_16x16x32_fp8_fp8(a[m2], bb[0], aR[m2], 0, 0, 0); \
      aZ[m2] = __builtin_amdgcn_mfma_f32_16x16x32_fp8_fp8(a[m2], bb[1], aZ[m2], 0, 0, 0); \
      aN[m2] = __builtin_amdgcn_mfma_f32_16x16x32_fp8_fp8(a[m2], bb[2], aN[m2], 0, 0, 0); \
    }                                                                        \
  }

// ---------------- one matmul phase: acc{R,Z,N} += A(256xK) @ W(96xK)^T, fp8, BK=128 ----------------
// 512 threads = 8 waves = 2 waves/SIMD: one wave's LDS/MFMA latency hides under the
// other's issue. Depth-2 (A,B) register pipeline with raw LDS-only barriers (R10).
template<int K, bool EMB>
__device__ __forceinline__ void mm_phase(SMem& sm, const u8* __restrict__ Asrc,
    const u8* __restrict__ W, int n0,
    f4v* aR, f4v* aZ, f4v* aN,
    const int* __restrict__ target, int bos, int u)
{
  const int t = threadIdx.x, lane = t & 63, wv = t >> 6;
  const int wm = wv >> 1, wg = wv & 1, li = lane & 15, q = lane >> 4;
  constexpr int NT = K / 128;   // 4 (L1 gi) or 8 (gh / L2,L3) -- always even
  uint64_t raE[4][2], raO[4][2];
  uint4 rbE[2], rbO[2];

  LOAD_A(raE, 0)
  LOAD_B(rbE, 0)
  LOAD_A(raO, 128)
  LOAD_B(rbO, 128)

#pragma unroll 1
  for (int it = 0; it < NT; it += 2) {
    BAR_LDS();
    WR_AB(raE, rbE)
    BAR_LDS();
    if (it + 2 < NT) { LOAD_A(raE, (it + 2) * 128) LOAD_B(rbE, (it + 2) * 128) }
    MFMA_TILE()
    BAR_LDS();
    WR_AB(raO, rbO)
    BAR_LDS();
    if (it + 3 < NT) { LOAD_A(raO, (it + 3) * 128) LOAD_B(rbO, (it + 3) * 128) }
    MFMA_TILE()
  }
}

// ---------------- merged layer stage: gi + gh + GRU update, FULL batch x 32j ----------------
template<int K1, bool L1f>
__device__ void do_L(SMem& sm, const u8* __restrict__ xsrc,
                     const u8* __restrict__ hbPrev, const float* __restrict__ hfPrev,
                     const u8* __restrict__ Wih, const u8* __restrict__ Whh,
                     const float* __restrict__ biP, const float* __restrict__ bhP,
                     float* __restrict__ hfOut, u8* __restrict__ hbOut,
                     const int* __restrict__ target, int bos, int u, int jt)
{
  const int j0 = jt * 32, n0 = jt * 96;
  f4v aR[4], aZ[4], aNi[4], aNh[4];
#pragma unroll
  for (int i = 0; i < 4; ++i) {
    aR[i] = f4v{0.f,0.f,0.f,0.f}; aZ[i] = f4v{0.f,0.f,0.f,0.f};
    aNi[i] = f4v{0.f,0.f,0.f,0.f}; aNh[i] = f4v{0.f,0.f,0.f,0.f};
  }
  mm_phase<K1, L1f>(sm, xsrc, Wih, n0, aR, aZ, aNi, target, bos, u);      // gi
  mm_phase<kH, false>(sm, hbPrev, Whh, n0, aR, aZ, aNh, target, bos, u);  // gh

  const int t = threadIdx.x, lane = t & 63, wv = t >> 6;
  const int wm = wv >> 1, wg = wv & 1, li = lane & 15, q = lane >> 4;
  const int j = j0 + 16 * wg + li;
  const int cr = n0 + 48 * wg + li;
  const float bR = biP[cr] + bhP[cr];
  const float bZ = biP[cr + 16] + bhP[cr + 16];
  const float biN = biP[cr + 32], bhN = bhP[cr + 32];
  float hold[4][4];
#pragma unroll
  for (int m2 = 0; m2 < 4; ++m2)
#pragma unroll
    for (int r = 0; r < 4; ++r) {
      int b = 64 * wm + 16 * m2 + 4 * q + r;
      hold[m2][r] = hfPrev[(size_t)b * kH + j];  // block-local, cached
    }
#pragma unroll
  for (int m2 = 0; m2 < 4; ++m2)
#pragma unroll
    for (int r = 0; r < 4; ++r) {
      int b = 64 * wm + 16 * m2 + 4 * q + r;
      float rg = 1.f / (1.f + __expf(-(aR[m2][r] * kInvSS + bR)));
      float zg = 1.f / (1.f + __expf(-(aZ[m2][r] * kInvSS + bZ)));
      float np = (aNi[m2][r] * kInvSS + biN) + rg * (aNh[m2][r] * kInvSS + bhN);
      float nh = 2.f / (1.f + __expf(-2.f * np)) - 1.f;   // tanh
      float hnew = (1.f - zg) * nh + zg * hold[m2][r];
      hfOut[(size_t)b * kH + j] = hnew;                   // local fp32, cached
      stv_u8(&hbOut[(size_t)b * kH + j], f2e4m3(hnew * kScale));  // cross-block fp8, MALL
    }
}

// ---------------- E stage: 2 tiles (32 rows) per 512-thread block ----------------
// R13 LDS-staged A-panels (one batched issue per panel, no serial chain); wave halves
// (wv>>2) own one 16-row tile each.
__device__ void do_E(SMem& sm, const u8* __restrict__ h3b, const u8* __restrict__ wo,
                     const float* __restrict__ b_out, const int* __restrict__ target,
                     float* __restrict__ lp, int u, int pairIdx)
{
  const int b0 = pairIdx * 32;
  const int t = threadIdx.x, lane = t & 63, wv = t >> 6;
  const int li = lane & 15, q = lane >> 4;
  const int half = wv >> 2, wq = wv & 3;

  // stage: threads 0..255 -> panel 0 (rows b0..b0+15), 256..511 -> panel 1
  {
    const int hh = t >> 8, tt = t & 255;
    const int row = tt & 15, th = tt >> 4;
    const int q2 = th & 3, kc = th >> 2;
    const u8* srcb = h3b + (size_t)(b0 + hh * 16 + row) * kH + q2 * 8;
    uint64_t s0 = ldv_u64(srcb + (0 * 4 + kc) * 32);
    uint64_t s1 = ldv_u64(srcb + (1 * 4 + kc) * 32);
    uint64_t s2 = ldv_u64(srcb + (2 * 4 + kc) * 32);
    uint64_t s3 = ldv_u64(srcb + (3 * 4 + kc) * 32);
    uint64_t s4 = ldv_u64(srcb + (4 * 4 + kc) * 32);
    uint64_t s5 = ldv_u64(srcb + (5 * 4 + kc) * 32);
    uint64_t s6 = ldv_u64(srcb + (6 * 4 + kc) * 32);
    uint64_t s7 = ldv_u64(srcb + (7 * 4 + kc) * 32);
    u8* db = &sm.mm.A[hh * 16384 + kc * 512 + row * 32 + q2 * 8];
    *(uint64_t*)(db + 0 * 2048) = s0;
    *(uint64_t*)(db + 1 * 2048) = s1;
    *(uint64_t*)(db + 2 * 2048) = s2;
    *(uint64_t*)(db + 3 * 2048) = s3;
    *(uint64_t*)(db + 4 * 2048) = s4;
    *(uint64_t*)(db + 5 * 2048) = s5;
    *(uint64_t*)(db + 6 * 2048) = s6;
    *(uint64_t*)(db + 7 * 2048) = s7;
  }
  __syncthreads();   // both A-panels in LDS

  f4v acc[6];
#pragma unroll
  for (int f = 0; f < 6; ++f) acc[f] = f4v{0.f, 0.f, 0.f, 0.f};

  const u8* wp = wo + (size_t)(96 * wq + li) * kH + q * 8;      // f stride = 16*kH
  const u8* al = &sm.mm.A[half * 16384 + li * 32 + q * 8];      // + (k0/32)*512

  uint64_t bE[6], bO[6];
#pragma unroll
  for (int f = 0; f < 6; ++f) bE[f] = *(const uint64_t*)(wp + (size_t)16 * f * kH);
#pragma unroll
  for (int f = 0; f < 6; ++f) bO[f] = *(const uint64_t*)(wp + (size_t)16 * f * kH + 32);

#pragma unroll 1
  for (int k0 = 0; k0 < kH; k0 += 64) {
    uint64_t bT[6];
    if (k0 + 64 < kH) {
#pragma unroll
      for (int f = 0; f < 6; ++f) bT[f] = *(const uint64_t*)(wp + (size_t)16 * f * kH + k0 + 64);
    }
    const uint64_t aE = *(const uint64_t*)(al + (k0 >> 5) * 512);
#pragma unroll
    for (int f = 0; f < 6; ++f)
      acc[f] = __builtin_amdgcn_mfma_f32_16x16x32_fp8_fp8((long)aE, (long)bE[f], acc[f], 0, 0, 0);
    if (k0 + 64 < kH) {
#pragma unroll
      for (int f = 0; f < 6; ++f) bE[f] = bT[f];
    }
    if (k0 + 96 < kH) {
#pragma unroll
      for (int f = 0; f < 6; ++f) bT[f] = *(const uint64_t*)(wp + (size_t)16 * f * kH + k0 + 96);
    }
    const uint64_t aO = *(const uint64_t*)(al + ((k0 + 32) >> 5) * 512);
#pragma unroll
    for (int f = 0; f < 6; ++f)
      acc[f] = __builtin_amdgcn_mfma_f32_16x16x32_fp8_fp8((long)aO, (long)bO[f], acc[f], 0, 0, 0);
    if (k0 + 96 < kH) {
#pragma unroll
      for (int f = 0; f < 6; ++f) bO[f] = bT[f];
    }
  }
  __syncthreads();   // all waves done reading LDS A-panels (logits alias)
#pragma unroll
  for (int f = 0; f < 6; ++f) {
    int n = 96 * wq + 16 * f + li;
    if (n < kV) {
      float bo = b_out[n];
#pragma unroll
      for (int r = 0; r < 4; ++r)
        sm.logits[(half * 16 + 4 * q + r) * 400 + n] = acc[f][r] * kInvSS + bo;
    }
  }
  __syncthreads();
  int m = half * 16 + 4 * wq + q;
  int b = b0 + m;
  float mx = -1e30f;
  for (int cc = li; cc < kV; cc += 16) mx = fmaxf(mx, sm.logits[m * 400 + cc]);
#pragma unroll
  for (int d = 1; d < 16; d <<= 1) mx = fmaxf(mx, __shfl_xor(mx, d, 16));
  float se = 0.f;
  for (int cc = li; cc < kV; cc += 16) se += __expf(sm.logits[m * 400 + cc] - mx);
#pragma unroll
  for (int d = 1; d < 16; d <<= 1) se += __shfl_xor(se, d, 16);
  int tgt = target[b * kT + u];
  float logp = sm.logits[m * 400 + tgt] - mx - __logf(se);
  if (li == 0) lp[b] += logp;
  __syncthreads();   // logits LDS reused next step
}

// ---------------- main persistent kernel: 512-thread blocks, 2 waves/SIMD ----------------
__global__ __launch_bounds__(512, 1) void rnn_main(Params P)
{
  __shared__ SMem sm;
  const int bid = blockIdx.x;
  const int bos = P.bosp[0];
  const size_t HS = (size_t)kB * kH;
  const int jt = bid & 31;

  for (int s = 0; s < kT + 3; ++s) {
    if (bid < 32) {                        // layer 1, u = s
      int u = s;
      if (u < kT)
        do_L<kE, true>(sm, P.embb,
                       P.h1b + (size_t)((u - 1) & 1) * HS, P.h1f + (size_t)((u - 1) & 1) * HS,
                       P.w1i, P.w1h, P.bi1, P.bh1,
                       P.h1f + (size_t)(u & 1) * HS, P.h1b + (size_t)(u & 1) * HS,
                       P.target, bos, u, jt);
    } else if (bid < 64) {                 // layer 2, u = s-1
      int u = s - 1;
      if (u >= 0 && u < kT)
        do_L<kH, false>(sm, P.h1b + (size_t)(u & 1) * HS,
                        P.h2b + (size_t)((u - 1) & 1) * HS, P.h2f + (size_t)((u - 1) & 1) * HS,
                        P.w2i, P.w2h, P.bi2, P.bh2,
                        P.h2f + (size_t)(u & 1) * HS, P.h2b + (size_t)(u & 1) * HS,
                        P.target, bos, u, jt);
    } else if (bid < 96) {                 // layer 3, u = s-2
      int u = s - 2;
      if (u >= 0 && u < kT)
        do_L<kH, false>(sm, P.h2b + (size_t)(u & 1) * HS,
                        P.h3b + (size_t)((u - 1) & 1) * HS, P.h3f + (size_t)((u - 1) & 1) * HS,
                        P.w3i, P.w3h, P.bi3, P.bh3,
                        P.h3f + (size_t)(u & 1) * HS, P.h3b + (size_t)(u & 1) * HS,
                        P.target, bos, u, jt);
    } else {                               // E, u = s-3, 2 tiles per block
      int u = s - 3;
      if (u >= 0 && u < kT)
        do_E(sm, P.h3b + (size_t)(u & 1) * HS, P.wout, P.b_out, P.target, P.lp, u, bid - 96);
    }
    gbar(P.acnt, P.gflag, (unsigned)s);
  }
}

// ---------------- conversion / init kernels (fp8 x32) ----------------
__global__ void k_conv_w(const float* __restrict__ w, u8* __restrict__ wp, int K, int logK) {
  int idx = blockIdx.x * 256 + threadIdx.x;
  if (idx >= kNG * K) return;
  int n = idx >> logK, k = idx & (K - 1);
  wp[(size_t)permn(n) * K + k] = f2e4m3(w[idx] * kScale);
}
__global__ void k_conv_b(const float* __restrict__ b, float* __restrict__ bp) {
  int idx = blockIdx.x * 256 + threadIdx.x;
  if (idx < kNG) bp[permn(idx)] = b[idx];
}
__global__ void k_conv_wout(const float* __restrict__ w, u8* __restrict__ wp) {
  int idx = blockIdx.x * 256 + threadIdx.x;
  if (idx >= 384 * kH) return;
  int n = idx >> 10, k = idx & 1023;
  wp[idx] = (n < kV) ? f2e4m3(w[(size_t)n * kH + k] * kScale) : (u8)0;
}
__global__ void k_conv_emb(const float* __restrict__ e, u8* __restrict__ ep) {
  int idx = blockIdx.x * 256 + threadIdx.x;
  if (idx < kV * kE) ep[idx] = f2e4m3(e[idx] * kScale);
}

extern "C" void kernel_launch(void* const* d_in, const int* in_sizes, int n_in,
                              void* d_out, int out_size, void* d_ws, size_t ws_size,
                              hipStream_t stream)
{
  const int*   target = (const int*)d_in[0];
  const int*   bosp   = (const int*)d_in[1];
  const float* emb    = (const float*)d_in[2];
  const float* w_ih1  = (const float*)d_in[3];
  const float* w_hh1  = (const float*)d_in[4];
  const float* b_ih1  = (const float*)d_in[5];
  const float* b_hh1  = (const float*)d_in[6];
  const float* w_ih2  = (const float*)d_in[7];
  const float* w_hh2  = (const float*)d_in[8];
  const float* b_ih2  = (const float*)d_in[9];
  const float* b_hh2  = (const float*)d_in[10];
  const float* w_ih3  = (const float*)d_in[11];
  const float* w_hh3  = (const float*)d_in[12];
  const float* b_ih3  = (const float*)d_in[13];
  const float* b_hh3  = (const float*)d_in[14];
  const float* w_out  = (const float*)d_in[15];
  const float* b_out  = (const float*)d_in[16];

  char* ws = (char*)d_ws;
  size_t off = 0;
  auto alloc = [&](size_t bytes) -> void* {
    void* p = ws + off;
    off = (off + bytes + 511) & ~(size_t)511;
    return p;
  };
  u8* w1i = (u8*)alloc((size_t)kNG * kE);
  u8* w1h = (u8*)alloc((size_t)kNG * kH);
  u8* w2i = (u8*)alloc((size_t)kNG * kH);
  u8* w2h = (u8*)alloc((size_t)kNG * kH);
  u8* w3i = (u8*)alloc((size_t)kNG * kH);
  u8* w3h = (u8*)alloc((size_t)kNG * kH);
  u8* wo  = (u8*)alloc((size_t)384 * kH);
  u8* eb  = (u8*)alloc((size_t)kV * kE);
  float* bi1 = (float*)alloc(kNG * 4);
  float* bh1 = (float*)alloc(kNG * 4);
  float* bi2 = (float*)alloc(kNG * 4);
  float* bh2 = (float*)alloc(kNG * 4);
  float* bi3 = (float*)alloc(kNG * 4);
  float* bh3 = (float*)alloc(kNG * 4);
  float* h1f = (float*)alloc((size_t)2 * kB * kH * 4);
  float* h2f = (float*)alloc((size_t)2 * kB * kH * 4);
  float* h3f = (float*)alloc((size_t)2 * kB * kH * 4);
  u8* h1b = (u8*)alloc((size_t)2 * kB * kH);
  u8* h2b = (u8*)alloc((size_t)2 * kB * kH);
  u8* h3b = (u8*)alloc((size_t)2 * kB * kH);
  unsigned* bar = (unsigned*)alloc(4096);
  (void)ws_size; (void)in_sizes; (void)n_in; (void)out_size;

  k_conv_w<<<(kNG * kE + 255) / 256, 256, 0, stream>>>(w_ih1, w1i, kE, 9);
  k_conv_w<<<(kNG * kH + 255) / 256, 256, 0, stream>>>(w_hh1, w1h, kH, 10);
  k_conv_w<<<(kNG * kH + 255) / 256, 256, 0, stream>>>(w_ih2, w2i, kH, 10);
  k_conv_w<<<(kNG * kH + 255) / 256, 256, 0, stream>>>(w_hh2, w2h, kH, 10);
  k_conv_w<<<(kNG * kH + 255) / 256, 256, 0, stream>>>(w_ih3, w3i, kH, 10);
  k_conv_w<<<(kNG * kH + 255) / 256, 256, 0, stream>>>(w_hh3, w3h, kH, 10);
  k_conv_b<<<(kNG + 255) / 256, 256, 0, stream>>>(b_ih1, bi1);
  k_conv_b<<<(kNG + 255) / 256, 256, 0, stream>>>(b_hh1, bh1);
  k_conv_b<<<(kNG + 255) / 256, 256, 0, stream>>>(b_ih2, bi2);
  k_conv_b<<<(kNG + 255) / 256, 256, 0, stream>>>(b_hh2, bh2);
  k_conv_b<<<(kNG + 255) / 256, 256, 0, stream>>>(b_ih3, bi3);
  k_conv_b<<<(kNG + 255) / 256, 256, 0, stream>>>(b_hh3, bh3);
  k_conv_wout<<<(384 * kH + 255) / 256, 256, 0, stream>>>(w_out, wo);
  k_conv_emb<<<(kV * kE + 255) / 256, 256, 0, stream>>>(emb, eb);

  hipMemsetAsync(h1f, 0, (size_t)3 * 2 * kB * kH * 4, stream);  // h1f,h2f,h3f contiguous
  hipMemsetAsync(h1b, 0, (size_t)3 * 2 * kB * kH, stream);      // h1b,h2b,h3b contiguous
  hipMemsetAsync(bar, 0, 4096, stream);
  hipMemsetAsync(d_out, 0, (size_t)kB * 4, stream);

  Params P;
  P.target = target; P.bosp = bosp; P.b_out = b_out;
  P.w1i = w1i; P.w1h = w1h; P.w2i = w2i; P.w2h = w2h; P.w3i = w3i; P.w3h = w3h;
  P.wout = wo; P.embb = eb;
  P.bi1 = bi1; P.bh1 = bh1; P.bi2 = bi2; P.bh2 = bh2; P.bi3 = bi3; P.bh3 = bh3;
  P.h1f = h1f; P.h2f = h2f; P.h3f = h3f;
  P.h1b = h1b; P.h2b = h2b; P.h3b = h3b;
  P.lp = (float*)d_out;
  P.acnt = bar; P.gflag = bar + 512;

  rnn_main<<<dim3(NB), dim3(512), 0, stream>>>(P);
}

// Round 16
// 3748.767 us; speedup vs baseline: 1.8445x; 1.8445x over previous
//
#include <hip/hip_runtime.h>
#include <hip/hip_bf16.h>
#include <cstdint>

// Problem constants
constexpr int kT = 128;    // sequence length
constexpr int kB = 256;    // batch
constexpr int kE = 512;    // embed dim
constexpr int kH = 1024;   // hidden
constexpr int kV = 348;    // vocab
constexpr int kNG = 3072;  // 3*H gate width
constexpr int NB = 208;    // 192 layer blocks + 16 E blocks (<=256 CUs, all resident)

constexpr float kScale = 32.f;        // fp8 storage scale (avoids e4m3 subnormal floor)
constexpr float kInvSS = 1.f / 1024.f; // 1/(kScale*kScale) applied to accumulators

typedef float f4v __attribute__((ext_vector_type(4)));   // MFMA accumulator
typedef unsigned short u16;
typedef unsigned char u8;

// float -> fp8 e4m3 (OCP) via HW packed convert; low byte of the pair
__device__ __forceinline__ u8 f2e4m3(float x) {
  int p = __builtin_amdgcn_cvt_pk_fp8_f32(x, x, 0, false);
  return (u8)(p & 0xff);
}

// device-coherent (cross-XCD) accessors: bypass L1/L2, hit MALL coherent point
__device__ __forceinline__ uint64_t ldv_u64(const void* p) {
  return __hip_atomic_load((const uint64_t*)p, __ATOMIC_RELAXED, __HIP_MEMORY_SCOPE_AGENT);
}
__device__ __forceinline__ void stv_u8(u8* p, u8 v) {
  __hip_atomic_store(p, v, __ATOMIC_RELAXED, __HIP_MEMORY_SCOPE_AGENT);
}

// gate-major n = gate*H + j  ->  interleaved col = 48*(j/16) + 16*gate + (j%16)
__device__ __forceinline__ int permn(int n) {
  int gate = n >> 10, j = n & 1023;
  return ((j >> 4) * 48) + gate * 16 + (j & 15);
}

struct Params {
  const int* target; const int* bosp; const float* b_out;
  const u8 *w1i, *w1h, *w2i, *w2h, *w3i, *w3h, *wout, *embb;  // fp8 x32
  const float *bi1, *bh1, *bi2, *bh2, *bi3, *bh3;
  float *h1f, *h2f, *h3f;       // [2][B][H] fp32 state (block-local, cached)
  u8    *h1b, *h2b, *h3b;       // [2][B][H] fp8 x32 state (cross-block, MALL)
  float *lp;                    // [B] output accumulator (= d_out)
  unsigned *acnt; unsigned *gflag;
};

// LDS: 128B row stride, XOR-swizzled at 8B granularity: slot(u,row) = u ^ (row&15).
// Tile reshaped 128x96 -> 64x192: A (MALL-uncached h-state) halves, B (L2-cached
// weights) doubles -- trades traffic on the saturated coherent path for the cached one.
union SMem {
  struct { u8 A[64 * 128]; u8 B[192 * 128]; } mm;   // 8KB + 24KB
  float logits[16 * 400];                           // 25.6KB (E reuses first 16KB for A-panel)
};

// ---- RAW workgroup barrier: waits LDS ops only, never drains vmcnt (R10-validated) ----
#define BAR_LDS() asm volatile("s_waitcnt lgkmcnt(0)\n\ts_barrier" ::: "memory")

// ---- grid barrier (R13 form): relaxed flag ops; full drain once per step ----
__device__ __forceinline__ void gbar(unsigned* acnt, unsigned* gflag, unsigned s) {
  asm volatile("s_waitcnt vmcnt(0)" ::: "memory");
  __syncthreads();
  if (threadIdx.x == 0) {
    const unsigned g = blockIdx.x & 31u;
    __hip_atomic_fetch_add(&acnt[g * 16], 1u, __ATOMIC_RELAXED, __HIP_MEMORY_SCOPE_AGENT);
    if (blockIdx.x == 0) {
      for (;;) {
        unsigned sum = 0;
#pragma unroll
        for (int i = 0; i < 32; ++i)
          sum += __hip_atomic_load(&acnt[i * 16], __ATOMIC_RELAXED, __HIP_MEMORY_SCOPE_AGENT);
        if (sum >= (unsigned)NB * (s + 1u)) break;
        __builtin_amdgcn_s_sleep(4);
      }
#pragma unroll
      for (int i = 0; i < 32; ++i)
        __hip_atomic_store(&gflag[i * 16], s + 1u, __ATOMIC_RELAXED, __HIP_MEMORY_SCOPE_AGENT);
    } else {
      while (__hip_atomic_load(&gflag[g * 16], __ATOMIC_RELAXED, __HIP_MEMORY_SCOPE_AGENT) <= s)
        __builtin_amdgcn_s_sleep(8);
    }
    asm volatile("" ::: "memory");
  }
  __syncthreads();
}

// ---- staging/compute macros: named register sets only (round-4 lesson), FIFO-ordered
// ---- per-tile issue (round-8 lesson). A = 64 rows (2 chunks/thr), B = 192 rows (6/thr).
#define LOAD_A(dst, k0)                                                      \
  _Pragma("unroll")                                                          \
  for (int p = 0; p < 2; ++p) {                                              \
    int id = p * 256 + t, r = id >> 3, c = id & 7;                           \
    if (EMB) {                                                               \
      int tok = (u == 0) ? bos : target[(b0 + r) * kT + (u - 1)];            \
      uint4 v = *(const uint4*)&Asrc[(size_t)tok * K + (k0) + c * 16];       \
      dst[p][0] = ((uint64_t)v.y << 32) | v.x;                               \
      dst[p][1] = ((uint64_t)v.w << 32) | v.z;                               \
    } else {                                                                 \
      const u8* srcp = Asrc + (size_t)(b0 + r) * kH + (k0) + c * 16;         \
      dst[p][0] = ldv_u64(srcp); dst[p][1] = ldv_u64(srcp + 8);              \
    }                                                                        \
  }

#define LOAD_B(dst, k0)                                                      \
  _Pragma("unroll")                                                          \
  for (int p = 0; p < 6; ++p) {                                              \
    int id = p * 256 + t, r = id >> 3, c = id & 7;                           \
    dst[p] = *(const uint4*)&W[(size_t)(n0 + r) * K + (k0) + c * 16];        \
  }

#define WR_AB(srcA, srcB)                                                    \
  _Pragma("unroll")                                                          \
  for (int p = 0; p < 2; ++p) {                                              \
    int id = p * 256 + t, r = id >> 3, c = id & 7;                           \
    const int u0 = c * 2, rx = r & 15;                                       \
    u8* base = &sm.mm.A[r * 128];                                            \
    *(uint64_t*)(base + 8 * (u0 ^ rx)) = srcA[p][0];                         \
    *(uint64_t*)(base + 8 * ((u0 + 1) ^ rx)) = srcA[p][1];                   \
  }                                                                          \
  _Pragma("unroll")                                                          \
  for (int p = 0; p < 6; ++p) {                                              \
    int id = p * 256 + t, r = id >> 3, c = id & 7;                           \
    const int u0 = c * 2, rx = r & 15;                                       \
    u8* base = &sm.mm.B[r * 128];                                            \
    *(uint64_t*)(base + 8 * (u0 ^ rx)) = (uint64_t)srcB[p].x | ((uint64_t)srcB[p].y << 32); \
    *(uint64_t*)(base + 8 * ((u0 + 1) ^ rx)) = (uint64_t)srcB[p].z | ((uint64_t)srcB[p].w << 32); \
  }

// wave wv (0..3) owns a 48-col group; all 64 A-rows; rows&15 == li on both operands.
#define MFMA_TILE()                                                          \
  _Pragma("unroll")                                                          \
  for (int kk = 0; kk < 128; kk += 32) {                                     \
    const int swz = 8 * (((kk >> 3) + q) ^ li);                              \
    long a[4], bb[3];                                                        \
    _Pragma("unroll")                                                        \
    for (int m2 = 0; m2 < 4; ++m2)                                           \
      a[m2] = *(const long*)&sm.mm.A[(16 * m2 + li) * 128 + swz];            \
    _Pragma("unroll")                                                        \
    for (int g = 0; g < 3; ++g)                                              \
      bb[g] = *(const long*)&sm.mm.B[(48 * wv + 16 * g + li) * 128 + swz];   \
    _Pragma("unroll")                                                        \
    for (int m2 = 0; m2 < 4; ++m2) {                                         \
      aR[m2] = __builtin_amdgcn_mfma_f32_16x16x32_fp8_fp8(a[m2], bb[0], aR[m2], 0, 0, 0); \
      aZ[m2] = __builtin_amdgcn_mfma_f32_16x16x32_fp8_fp8(a[m2], bb[1], aZ[m2], 0, 0, 0); \
      aN[m2] = __builtin_amdgcn_mfma_f32_16x16x32_fp8_fp8(a[m2], bb[2], aN[m2], 0, 0, 0); \
    }                                                                        \
  }

// ---------------- one matmul phase: acc{R,Z,N} += A(64xK) @ W(192xK)^T, fp8, BK=128 ----------------
template<int K, bool EMB>
__device__ __forceinline__ void mm_phase(SMem& sm, const u8* __restrict__ Asrc,
    const u8* __restrict__ W, int b0, int n0,
    f4v* aR, f4v* aZ, f4v* aN,
    const int* __restrict__ target, int bos, int u)
{
  const int t = threadIdx.x, lane = t & 63, wv = t >> 6;
  const int li = lane & 15, q = lane >> 4;
  constexpr int NT = K / 128;   // 4 (L1 gi) or 8 (gh / L2,L3) -- always even
  uint64_t raE[2][2], raO[2][2];
  uint4 rbE[6], rbO[6];

  LOAD_A(raE, 0)
  LOAD_B(rbE, 0)
  LOAD_A(raO, 128)
  LOAD_B(rbO, 128)

#pragma unroll 1
  for (int it = 0; it < NT; it += 2) {
    BAR_LDS();
    WR_AB(raE, rbE)                       // counted vmcnt: waits exactly {A(it),B(it)}
    BAR_LDS();
    if (it + 2 < NT) { LOAD_A(raE, (it + 2) * 128) LOAD_B(rbE, (it + 2) * 128) }
    MFMA_TILE()
    BAR_LDS();
    WR_AB(raO, rbO)
    BAR_LDS();
    if (it + 3 < NT) { LOAD_A(raO, (it + 3) * 128) LOAD_B(rbO, (it + 3) * 128) }
    MFMA_TILE()
  }
}

// ---------------- merged layer stage: gi + gh + GRU update, tile 64b x 64j ----------------
template<int K1, bool L1f>
__device__ void do_L(SMem& sm, const u8* __restrict__ xsrc,
                     const u8* __restrict__ hbPrev, const float* __restrict__ hfPrev,
                     const u8* __restrict__ Wih, const u8* __restrict__ Whh,
                     const float* __restrict__ biP, const float* __restrict__ bhP,
                     float* __restrict__ hfOut, u8* __restrict__ hbOut,
                     const int* __restrict__ target, int bos, int u, int mt, int jt)
{
  const int b0 = mt * 64, j0 = jt * 64, n0 = jt * 192;
  f4v aR[4], aZ[4], aNi[4], aNh[4];
#pragma unroll
  for (int i = 0; i < 4; ++i) {
    aR[i] = f4v{0.f,0.f,0.f,0.f}; aZ[i] = f4v{0.f,0.f,0.f,0.f};
    aNi[i] = f4v{0.f,0.f,0.f,0.f}; aNh[i] = f4v{0.f,0.f,0.f,0.f};
  }
  mm_phase<K1, L1f>(sm, xsrc, Wih, b0, n0, aR, aZ, aNi, target, bos, u);      // gi
  mm_phase<kH, false>(sm, hbPrev, Whh, b0, n0, aR, aZ, aNh, target, bos, u);  // gh

  const int t = threadIdx.x, lane = t & 63, wv = t >> 6;
  const int li = lane & 15, q = lane >> 4;
  const int j = j0 + 16 * wv + li;
  const int cr = n0 + 48 * wv + li;
  const float bR = biP[cr] + bhP[cr];
  const float bZ = biP[cr + 16] + bhP[cr + 16];
  const float biN = biP[cr + 32], bhN = bhP[cr + 32];
  float hold[4][4];
#pragma unroll
  for (int m2 = 0; m2 < 4; ++m2)
#pragma unroll
    for (int r = 0; r < 4; ++r) {
      int b = b0 + 16 * m2 + 4 * q + r;
      hold[m2][r] = hfPrev[(size_t)b * kH + j];  // block-local, cached
    }
#pragma unroll
  for (int m2 = 0; m2 < 4; ++m2)
#pragma unroll
    for (int r = 0; r < 4; ++r) {
      int b = b0 + 16 * m2 + 4 * q + r;
      float rg = 1.f / (1.f + __expf(-(aR[m2][r] * kInvSS + bR)));
      float zg = 1.f / (1.f + __expf(-(aZ[m2][r] * kInvSS + bZ)));
      float np = (aNi[m2][r] * kInvSS + biN) + rg * (aNh[m2][r] * kInvSS + bhN);
      float nh = 2.f / (1.f + __expf(-2.f * np)) - 1.f;   // tanh
      float hnew = (1.f - zg) * nh + zg * hold[m2][r];
      hfOut[(size_t)b * kH + j] = hnew;                   // local fp32, cached
      stv_u8(&hbOut[(size_t)b * kH + j], f2e4m3(hnew * kScale));  // cross-block fp8, MALL
    }
}

// ---------------- E stage: logits + log_softmax + gather (16 rows/block) ----------------
// R13 form; A-panel staged at the union base (first 16KB), batched single issue.
__device__ void do_E(SMem& sm, const u8* __restrict__ h3b, const u8* __restrict__ wo,
                     const float* __restrict__ b_out, const int* __restrict__ target,
                     float* __restrict__ lp, int u, int tile)
{
  const int b0 = tile * 16;
  const int t = threadIdx.x, lane = t & 63, wv = t >> 6;
  const int li = lane & 15, q = lane >> 4;
  u8* pan = (u8*)&sm;                        // 16KB A-panel at union base

  {
    const int row = t & 15, th = t >> 4;
    const int q2 = th & 3, kc = th >> 2;
    const u8* srcb = h3b + (size_t)(b0 + row) * kH + q2 * 8;
    uint64_t s0 = ldv_u64(srcb + (0 * 4 + kc) * 32);
    uint64_t s1 = ldv_u64(srcb + (1 * 4 + kc) * 32);
    uint64_t s2 = ldv_u64(srcb + (2 * 4 + kc) * 32);
    uint64_t s3 = ldv_u64(srcb + (3 * 4 + kc) * 32);
    uint64_t s4 = ldv_u64(srcb + (4 * 4 + kc) * 32);
    uint64_t s5 = ldv_u64(srcb + (5 * 4 + kc) * 32);
    uint64_t s6 = ldv_u64(srcb + (6 * 4 + kc) * 32);
    uint64_t s7 = ldv_u64(srcb + (7 * 4 + kc) * 32);
    u8* db = pan + kc * 512 + row * 32 + q2 * 8;   // tile stride 4*512=2048
    *(uint64_t*)(db + 0 * 2048) = s0;
    *(uint64_t*)(db + 1 * 2048) = s1;
    *(uint64_t*)(db + 2 * 2048) = s2;
    *(uint64_t*)(db + 3 * 2048) = s3;
    *(uint64_t*)(db + 4 * 2048) = s4;
    *(uint64_t*)(db + 5 * 2048) = s5;
    *(uint64_t*)(db + 6 * 2048) = s6;
    *(uint64_t*)(db + 7 * 2048) = s7;
  }
  __syncthreads();   // A-panel in LDS

  f4v acc[6];
#pragma unroll
  for (int f = 0; f < 6; ++f) acc[f] = f4v{0.f, 0.f, 0.f, 0.f};

  const u8* wp = wo + (size_t)(96 * wv + li) * kH + q * 8;   // f stride = 16*kH
  const u8* al = pan + li * 32 + q * 8;                      // + (k0/32)*512

  uint64_t bE[6], bO[6];
#pragma unroll
  for (int f = 0; f < 6; ++f) bE[f] = *(const uint64_t*)(wp + (size_t)16 * f * kH);
#pragma unroll
  for (int f = 0; f < 6; ++f) bO[f] = *(const uint64_t*)(wp + (size_t)16 * f * kH + 32);

#pragma unroll 1
  for (int k0 = 0; k0 < kH; k0 += 64) {
    uint64_t bT[6];
    if (k0 + 64 < kH) {
#pragma unroll
      for (int f = 0; f < 6; ++f) bT[f] = *(const uint64_t*)(wp + (size_t)16 * f * kH + k0 + 64);
    }
    const uint64_t aE = *(const uint64_t*)(al + (k0 >> 5) * 512);
#pragma unroll
    for (int f = 0; f < 6; ++f)
      acc[f] = __builtin_amdgcn_mfma_f32_16x16x32_fp8_fp8((long)aE, (long)bE[f], acc[f], 0, 0, 0);
    if (k0 + 64 < kH) {
#pragma unroll
      for (int f = 0; f < 6; ++f) bE[f] = bT[f];
    }
    if (k0 + 96 < kH) {
#pragma unroll
      for (int f = 0; f < 6; ++f) bT[f] = *(const uint64_t*)(wp + (size_t)16 * f * kH + k0 + 96);
    }
    const uint64_t aO = *(const uint64_t*)(al + ((k0 + 32) >> 5) * 512);
#pragma unroll
    for (int f = 0; f < 6; ++f)
      acc[f] = __builtin_amdgcn_mfma_f32_16x16x32_fp8_fp8((long)aO, (long)bO[f], acc[f], 0, 0, 0);
    if (k0 + 96 < kH) {
#pragma unroll
      for (int f = 0; f < 6; ++f) bO[f] = bT[f];
    }
  }
  __syncthreads();   // done reading A-panel (logits region aliases it)
#pragma unroll
  for (int f = 0; f < 6; ++f) {
    int n = 96 * wv + 16 * f + li;
    if (n < kV) {
      float bo = b_out[n];
#pragma unroll
      for (int r = 0; r < 4; ++r)
        sm.logits[(4 * q + r) * 400 + n] = acc[f][r] * kInvSS + bo;
    }
  }
  __syncthreads();
  int m = 4 * wv + q;
  int b = b0 + m;
  float mx = -1e30f;
  for (int cc = li; cc < kV; cc += 16) mx = fmaxf(mx, sm.logits[m * 400 + cc]);
#pragma unroll
  for (int d = 1; d < 16; d <<= 1) mx = fmaxf(mx, __shfl_xor(mx, d, 16));
  float se = 0.f;
  for (int cc = li; cc < kV; cc += 16) se += __expf(sm.logits[m * 400 + cc] - mx);
#pragma unroll
  for (int d = 1; d < 16; d <<= 1) se += __shfl_xor(se, d, 16);
  int tgt = target[b * kT + u];
  float logp = sm.logits[m * 400 + tgt] - mx - __logf(se);
  if (li == 0) lp[b] += logp;
  __syncthreads();   // logits LDS reused next step
}

// ---------------- main persistent kernel ----------------
__global__ __launch_bounds__(256, 1) void rnn_main(Params P)
{
  __shared__ SMem sm;
  const int bid = blockIdx.x;
  const int bos = P.bosp[0];
  const size_t HS = (size_t)kB * kH;

  // 64 blocks/layer = 4 mt x 16 jt; mt-quad sharing a weight panel sits 16 bids
  // apart (same XCD under bid%8 round-robin -> L2 absorbs the 4x weight re-read).
  const int local = bid & 63;
  const int mt = (local >> 4) & 3;
  const int jt = local & 15;

  for (int s = 0; s < kT + 3; ++s) {
    if (bid < 64) {                        // layer 1, u = s
      int u = s;
      if (u < kT)
        do_L<kE, true>(sm, P.embb,
                       P.h1b + (size_t)((u - 1) & 1) * HS, P.h1f + (size_t)((u - 1) & 1) * HS,
                       P.w1i, P.w1h, P.bi1, P.bh1,
                       P.h1f + (size_t)(u & 1) * HS, P.h1b + (size_t)(u & 1) * HS,
                       P.target, bos, u, mt, jt);
    } else if (bid < 128) {                // layer 2, u = s-1
      int u = s - 1;
      if (u >= 0 && u < kT)
        do_L<kH, false>(sm, P.h1b + (size_t)(u & 1) * HS,
                        P.h2b + (size_t)((u - 1) & 1) * HS, P.h2f + (size_t)((u - 1) & 1) * HS,
                        P.w2i, P.w2h, P.bi2, P.bh2,
                        P.h2f + (size_t)(u & 1) * HS, P.h2b + (size_t)(u & 1) * HS,
                        P.target, bos, u, mt, jt);
    } else if (bid < 192) {                // layer 3, u = s-2
      int u = s - 2;
      if (u >= 0 && u < kT)
        do_L<kH, false>(sm, P.h2b + (size_t)(u & 1) * HS,
                        P.h3b + (size_t)((u - 1) & 1) * HS, P.h3f + (size_t)((u - 1) & 1) * HS,
                        P.w3i, P.w3h, P.bi3, P.bh3,
                        P.h3f + (size_t)(u & 1) * HS, P.h3b + (size_t)(u & 1) * HS,
                        P.target, bos, u, mt, jt);
    } else {                               // E, u = s-3
      int u = s - 3;
      if (u >= 0 && u < kT)
        do_E(sm, P.h3b + (size_t)(u & 1) * HS, P.wout, P.b_out, P.target, P.lp, u, bid - 192);
    }
    gbar(P.acnt, P.gflag, (unsigned)s);
  }
}

// ---------------- conversion / init kernels (fp8 x32) ----------------
__global__ void k_conv_w(const float* __restrict__ w, u8* __restrict__ wp, int K, int logK) {
  int idx = blockIdx.x * 256 + threadIdx.x;
  if (idx >= kNG * K) return;
  int n = idx >> logK, k = idx & (K - 1);
  wp[(size_t)permn(n) * K + k] = f2e4m3(w[idx] * kScale);
}
__global__ void k_conv_b(const float* __restrict__ b, float* __restrict__ bp) {
  int idx = blockIdx.x * 256 + threadIdx.x;
  if (idx < kNG) bp[permn(idx)] = b[idx];
}
__global__ void k_conv_wout(const float* __restrict__ w, u8* __restrict__ wp) {
  int idx = blockIdx.x * 256 + threadIdx.x;
  if (idx >= 384 * kH) return;
  int n = idx >> 10, k = idx & 1023;
  wp[idx] = (n < kV) ? f2e4m3(w[(size_t)n * kH + k] * kScale) : (u8)0;
}
__global__ void k_conv_emb(const float* __restrict__ e, u8* __restrict__ ep) {
  int idx = blockIdx.x * 256 + threadIdx.x;
  if (idx < kV * kE) ep[idx] = f2e4m3(e[idx] * kScale);
}

extern "C" void kernel_launch(void* const* d_in, const int* in_sizes, int n_in,
                              void* d_out, int out_size, void* d_ws, size_t ws_size,
                              hipStream_t stream)
{
  const int*   target = (const int*)d_in[0];
  const int*   bosp   = (const int*)d_in[1];
  const float* emb    = (const float*)d_in[2];
  const float* w_ih1  = (const float*)d_in[3];
  const float* w_hh1  = (const float*)d_in[4];
  const float* b_ih1  = (const float*)d_in[5];
  const float* b_hh1  = (const float*)d_in[6];
  const float* w_ih2  = (const float*)d_in[7];
  const float* w_hh2  = (const float*)d_in[8];
  const float* b_ih2  = (const float*)d_in[9];
  const float* b_hh2  = (const float*)d_in[10];
  const float* w_ih3  = (const float*)d_in[11];
  const float* w_hh3  = (const float*)d_in[12];
  const float* b_ih3  = (const float*)d_in[13];
  const float* b_hh3  = (const float*)d_in[14];
  const float* w_out  = (const float*)d_in[15];
  const float* b_out  = (const float*)d_in[16];

  char* ws = (char*)d_ws;
  size_t off = 0;
  auto alloc = [&](size_t bytes) -> void* {
    void* p = ws + off;
    off = (off + bytes + 511) & ~(size_t)511;
    return p;
  };
  u8* w1i = (u8*)alloc((size_t)kNG * kE);
  u8* w1h = (u8*)alloc((size_t)kNG * kH);
  u8* w2i = (u8*)alloc((size_t)kNG * kH);
  u8* w2h = (u8*)alloc((size_t)kNG * kH);
  u8* w3i = (u8*)alloc((size_t)kNG * kH);
  u8* w3h = (u8*)alloc((size_t)kNG * kH);
  u8* wo  = (u8*)alloc((size_t)384 * kH);
  u8* eb  = (u8*)alloc((size_t)kV * kE);
  float* bi1 = (float*)alloc(kNG * 4);
  float* bh1 = (float*)alloc(kNG * 4);
  float* bi2 = (float*)alloc(kNG * 4);
  float* bh2 = (float*)alloc(kNG * 4);
  float* bi3 = (float*)alloc(kNG * 4);
  float* bh3 = (float*)alloc(kNG * 4);
  float* h1f = (float*)alloc((size_t)2 * kB * kH * 4);
  float* h2f = (float*)alloc((size_t)2 * kB * kH * 4);
  float* h3f = (float*)alloc((size_t)2 * kB * kH * 4);
  u8* h1b = (u8*)alloc((size_t)2 * kB * kH);
  u8* h2b = (u8*)alloc((size_t)2 * kB * kH);
  u8* h3b = (u8*)alloc((size_t)2 * kB * kH);
  unsigned* bar = (unsigned*)alloc(4096);
  (void)ws_size; (void)in_sizes; (void)n_in; (void)out_size;

  k_conv_w<<<(kNG * kE + 255) / 256, 256, 0, stream>>>(w_ih1, w1i, kE, 9);
  k_conv_w<<<(kNG * kH + 255) / 256, 256, 0, stream>>>(w_hh1, w1h, kH, 10);
  k_conv_w<<<(kNG * kH + 255) / 256, 256, 0, stream>>>(w_ih2, w2i, kH, 10);
  k_conv_w<<<(kNG * kH + 255) / 256, 256, 0, stream>>>(w_hh2, w2h, kH, 10);
  k_conv_w<<<(kNG * kH + 255) / 256, 256, 0, stream>>>(w_ih3, w3i, kH, 10);
  k_conv_w<<<(kNG * kH + 255) / 256, 256, 0, stream>>>(w_hh3, w3h, kH, 10);
  k_conv_b<<<(kNG + 255) / 256, 256, 0, stream>>>(b_ih1, bi1);
  k_conv_b<<<(kNG + 255) / 256, 256, 0, stream>>>(b_hh1, bh1);
  k_conv_b<<<(kNG + 255) / 256, 256, 0, stream>>>(b_ih2, bi2);
  k_conv_b<<<(kNG + 255) / 256, 256, 0, stream>>>(b_hh2, bh2);
  k_conv_b<<<(kNG + 255) / 256, 256, 0, stream>>>(b_ih3, bi3);
  k_conv_b<<<(kNG + 255) / 256, 256, 0, stream>>>(b_hh3, bh3);
  k_conv_wout<<<(384 * kH + 255) / 256, 256, 0, stream>>>(w_out, wo);
  k_conv_emb<<<(kV * kE + 255) / 256, 256, 0, stream>>>(emb, eb);

  hipMemsetAsync(h1f, 0, (size_t)3 * 2 * kB * kH * 4, stream);  // h1f,h2f,h3f contiguous
  hipMemsetAsync(h1b, 0, (size_t)3 * 2 * kB * kH, stream);      // h1b,h2b,h3b contiguous
  hipMemsetAsync(bar, 0, 4096, stream);
  hipMemsetAsync(d_out, 0, (size_t)kB * 4, stream);

  Params P;
  P.target = target; P.bosp = bosp; P.b_out = b_out;
  P.w1i = w1i; P.w1h = w1h; P.w2i = w2i; P.w2h = w2h; P.w3i = w3i; P.w3h = w3h;
  P.wout = wo; P.embb = eb;
  P.bi1 = bi1; P.bh1 = bh1; P.bi2 = bi2; P.bh2 = bh2; P.bi3 = bi3; P.bh3 = bh3;
  P.h1f = h1f; P.h2f = h2f; P.h3f = h3f;
  P.h1b = h1b; P.h2b = h2b; P.h3b = h3b;
  P.lp = (float*)d_out;
  P.acnt = bar; P.gflag = bar + 512;

  rnn_main<<<dim3(NB), dim3(256), 0, stream>>>(P);
}

// Round 17
// 3741.588 us; speedup vs baseline: 1.8481x; 1.0019x over previous
//
#include <hip/hip_runtime.h>
#include <hip/hip_bf16.h>
#include <cstdint>

// Problem constants
constexpr int kT = 128;    // sequence length
constexpr int kB = 256;    // batch
constexpr int kE = 512;    // embed dim
constexpr int kH = 1024;   // hidden
constexpr int kV = 348;    // vocab
constexpr int kNG = 3072;  // 3*H gate width
constexpr int NB = 208;    // 192 layer blocks + 16 E blocks (<=256 CUs, all resident)

constexpr float kScale = 32.f;        // fp8 storage scale (avoids e4m3 subnormal floor)
constexpr float kInvSS = 1.f / 1024.f; // 1/(kScale*kScale) applied to accumulators

typedef float f4v __attribute__((ext_vector_type(4)));   // MFMA accumulator
typedef unsigned short u16;
typedef unsigned char u8;

// float -> fp8 e4m3 (OCP) via HW packed convert; low byte of the pair
__device__ __forceinline__ u8 f2e4m3(float x) {
  int p = __builtin_amdgcn_cvt_pk_fp8_f32(x, x, 0, false);
  return (u8)(p & 0xff);
}

// device-coherent (cross-XCD) accessors: bypass L1/L2, hit MALL coherent point
__device__ __forceinline__ uint64_t ldv_u64(const void* p) {
  return __hip_atomic_load((const uint64_t*)p, __ATOMIC_RELAXED, __HIP_MEMORY_SCOPE_AGENT);
}
__device__ __forceinline__ void stv_u8(u8* p, u8 v) {
  __hip_atomic_store(p, v, __ATOMIC_RELAXED, __HIP_MEMORY_SCOPE_AGENT);
}

// gate-major n = gate*H + j  ->  interleaved col = 48*(j/16) + 16*gate + (j%16)
__device__ __forceinline__ int permn(int n) {
  int gate = n >> 10, j = n & 1023;
  return ((j >> 4) * 48) + gate * 16 + (j & 15);
}

struct Params {
  const int* target; const int* bosp; const float* b_out;
  const u8 *w1i, *w1h, *w2i, *w2h, *w3i, *w3h, *wout, *embb;  // fp8 x32
  const float *bi1, *bh1, *bi2, *bh2, *bi3, *bh3;
  float *h1f, *h2f, *h3f;       // [2][B][H] fp32 state (block-local, cached)
  u8    *h1b, *h2b, *h3b;       // [2][B][H] fp8 x32 state (cross-block, MALL)
  float *lp;                    // [B] output accumulator (= d_out)
  unsigned *acnt; unsigned *gflag;
};

// LDS: DOUBLE-BUFFERED tiles. Per buffer: A(64x128) at +0, B(192x128) at +8192.
// XOR swizzle at 8B granularity: slot(u,row) = u ^ (row&15) (validated R2/R3).
// Single barrier per K-tile: WR of tile t+1 overlaps MFMA of tile t in the other buffer.
union SMem {
  u8 buf[2][32 * 1024];      // 64KB
  float logits[16 * 400];    // 25.6KB (E stage aliases buffer 0)
};

// ---- RAW workgroup barrier: waits LDS ops only, never drains vmcnt (R10-validated) ----
#define BAR_LDS() asm volatile("s_waitcnt lgkmcnt(0)\n\ts_barrier" ::: "memory")

// ---- grid barrier (R13 form): relaxed flag ops; full drain once per step ----
__device__ __forceinline__ void gbar(unsigned* acnt, unsigned* gflag, unsigned s) {
  asm volatile("s_waitcnt vmcnt(0)" ::: "memory");
  __syncthreads();
  if (threadIdx.x == 0) {
    const unsigned g = blockIdx.x & 31u;
    __hip_atomic_fetch_add(&acnt[g * 16], 1u, __ATOMIC_RELAXED, __HIP_MEMORY_SCOPE_AGENT);
    if (blockIdx.x == 0) {
      for (;;) {
        unsigned sum = 0;
#pragma unroll
        for (int i = 0; i < 32; ++i)
          sum += __hip_atomic_load(&acnt[i * 16], __ATOMIC_RELAXED, __HIP_MEMORY_SCOPE_AGENT);
        if (sum >= (unsigned)NB * (s + 1u)) break;
        __builtin_amdgcn_s_sleep(4);
      }
#pragma unroll
      for (int i = 0; i < 32; ++i)
        __hip_atomic_store(&gflag[i * 16], s + 1u, __ATOMIC_RELAXED, __HIP_MEMORY_SCOPE_AGENT);
    } else {
      while (__hip_atomic_load(&gflag[g * 16], __ATOMIC_RELAXED, __HIP_MEMORY_SCOPE_AGENT) <= s)
        __builtin_amdgcn_s_sleep(8);
    }
    asm volatile("" ::: "memory");
  }
  __syncthreads();
}

// ---- staging/compute macros: ONE register set (WR drains regs, reload for t+2 --
// still ~1.5 tiles of load cover, single clean vmcnt FIFO stream).
// A = 64 rows (2 chunks/thr), B = 192 rows (6/thr). R16 tile shape kept.
#define LOAD_A(k0)                                                           \
  _Pragma("unroll")                                                          \
  for (int p = 0; p < 2; ++p) {                                              \
    int id = p * 256 + t, r = id >> 3, c = id & 7;                           \
    if (EMB) {                                                               \
      int tok = (u == 0) ? bos : target[(b0 + r) * kT + (u - 1)];            \
      uint4 v = *(const uint4*)&Asrc[(size_t)tok * K + (k0) + c * 16];       \
      ra[p][0] = ((uint64_t)v.y << 32) | v.x;                                \
      ra[p][1] = ((uint64_t)v.w << 32) | v.z;                                \
    } else {                                                                 \
      const u8* srcp = Asrc + (size_t)(b0 + r) * kH + (k0) + c * 16;         \
      ra[p][0] = ldv_u64(srcp); ra[p][1] = ldv_u64(srcp + 8);                \
    }                                                                        \
  }

#define LOAD_B(k0)                                                           \
  _Pragma("unroll")                                                          \
  for (int p = 0; p < 6; ++p) {                                              \
    int id = p * 256 + t, r = id >> 3, c = id & 7;                           \
    rb[p] = *(const uint4*)&W[(size_t)(n0 + r) * K + (k0) + c * 16];         \
  }

#define WR_AB(bi)                                                            \
  {                                                                          \
    u8* Abase = &sm.buf[bi][0];                                              \
    u8* Bbase = &sm.buf[bi][8192];                                           \
    _Pragma("unroll")                                                        \
    for (int p = 0; p < 2; ++p) {                                            \
      int id = p * 256 + t, r = id >> 3, c = id & 7;                         \
      const int u0 = c * 2, rx = r & 15;                                     \
      u8* base = Abase + r * 128;                                            \
      *(uint64_t*)(base + 8 * (u0 ^ rx)) = ra[p][0];                         \
      *(uint64_t*)(base + 8 * ((u0 + 1) ^ rx)) = ra[p][1];                   \
    }                                                                        \
    _Pragma("unroll")                                                        \
    for (int p = 0; p < 6; ++p) {                                            \
      int id = p * 256 + t, r = id >> 3, c = id & 7;                         \
      const int u0 = c * 2, rx = r & 15;                                     \
      u8* base = Bbase + r * 128;                                            \
      *(uint64_t*)(base + 8 * (u0 ^ rx)) = (uint64_t)rb[p].x | ((uint64_t)rb[p].y << 32); \
      *(uint64_t*)(base + 8 * ((u0 + 1) ^ rx)) = (uint64_t)rb[p].z | ((uint64_t)rb[p].w << 32); \
    }                                                                        \
  }

// wave wv (0..3) owns a 48-col group; all 64 A-rows; rows&15 == li on both operands.
#define MFMA_TILE(bi)                                                        \
  {                                                                          \
    const u8* Abase = &sm.buf[bi][0];                                        \
    const u8* Bbase = &sm.buf[bi][8192];                                     \
    _Pragma("unroll")                                                        \
    for (int kk = 0; kk < 128; kk += 32) {                                   \
      const int swz = 8 * (((kk >> 3) + q) ^ li);                            \
      long a[4], bb[3];                                                      \
      _Pragma("unroll")                                                      \
      for (int m2 = 0; m2 < 4; ++m2)                                         \
        a[m2] = *(const long*)(Abase + (16 * m2 + li) * 128 + swz);          \
      _Pragma("unroll")                                                      \
      for (int g = 0; g < 3; ++g)                                            \
        bb[g] = *(const long*)(Bbase + (48 * wv + 16 * g + li) * 128 + swz); \
      _Pragma("unroll")                                                      \
      for (int m2 = 0; m2 < 4; ++m2) {                                       \
        aR[m2] = __builtin_amdgcn_mfma_f32_16x16x32_fp8_fp8(a[m2], bb[0], aR[m2], 0, 0, 0); \
        aZ[m2] = __builtin_amdgcn_mfma_f32_16x16x32_fp8_fp8(a[m2], bb[1], aZ[m2], 0, 0, 0); \
        aN[m2] = __builtin_amdgcn_mfma_f32_16x16x32_fp8_fp8(a[m2], bb[2], aN[m2], 0, 0, 0); \
      }                                                                      \
    }                                                                        \
  }

// ---------------- one matmul phase: acc{R,Z,N} += A(64xK) @ W(192xK)^T, fp8, BK=128 ----------------
// LDS double-buffer, ONE barrier per tile. Hazard audit: WR buf[(t+1)&1] targets the
// buffer last read in tile t-1 (drained by that tile's barrier); MFMA buf[t&1] reads
// writes from tile t-1 (visible after its barrier); gi->gh boundary covered by gi's
// final barrier.
template<int K, bool EMB>
__device__ __forceinline__ void mm_phase(SMem& sm, const u8* __restrict__ Asrc,
    const u8* __restrict__ W, int b0, int n0,
    f4v* aR, f4v* aZ, f4v* aN,
    const int* __restrict__ target, int bos, int u)
{
  const int t = threadIdx.x, lane = t & 63, wv = t >> 6;
  const int li = lane & 15, q = lane >> 4;
  constexpr int NT = K / 128;   // 4 (L1 gi) or 8 (gh / L2,L3)
  uint64_t ra[2][2];
  uint4 rb[6];

  LOAD_A(0) LOAD_B(0)
  WR_AB(0)                       // waits tile0 loads (only stream entries)
  LOAD_A(128) LOAD_B(128)        // tile1 in flight across the barrier
  BAR_LDS();

#pragma unroll 1
  for (int it = 0; it < NT; ++it) {
    if (it + 1 < NT) { WR_AB((it + 1) & 1) }                 // waits tile it+1 loads
    if (it + 2 < NT) { LOAD_A((it + 2) * 128) LOAD_B((it + 2) * 128) }
    MFMA_TILE(it & 1)
    BAR_LDS();
  }
}

// ---------------- merged layer stage: gi + gh + GRU update, tile 64b x 64j ----------------
template<int K1, bool L1f>
__device__ void do_L(SMem& sm, const u8* __restrict__ xsrc,
                     const u8* __restrict__ hbPrev, const float* __restrict__ hfPrev,
                     const u8* __restrict__ Wih, const u8* __restrict__ Whh,
                     const float* __restrict__ biP, const float* __restrict__ bhP,
                     float* __restrict__ hfOut, u8* __restrict__ hbOut,
                     const int* __restrict__ target, int bos, int u, int mt, int jt)
{
  const int b0 = mt * 64, j0 = jt * 64, n0 = jt * 192;
  f4v aR[4], aZ[4], aNi[4], aNh[4];
#pragma unroll
  for (int i = 0; i < 4; ++i) {
    aR[i] = f4v{0.f,0.f,0.f,0.f}; aZ[i] = f4v{0.f,0.f,0.f,0.f};
    aNi[i] = f4v{0.f,0.f,0.f,0.f}; aNh[i] = f4v{0.f,0.f,0.f,0.f};
  }
  mm_phase<K1, L1f>(sm, xsrc, Wih, b0, n0, aR, aZ, aNi, target, bos, u);      // gi
  mm_phase<kH, false>(sm, hbPrev, Whh, b0, n0, aR, aZ, aNh, target, bos, u);  // gh

  const int t = threadIdx.x, lane = t & 63, wv = t >> 6;
  const int li = lane & 15, q = lane >> 4;
  const int j = j0 + 16 * wv + li;
  const int cr = n0 + 48 * wv + li;
  const float bR = biP[cr] + bhP[cr];
  const float bZ = biP[cr + 16] + bhP[cr + 16];
  const float biN = biP[cr + 32], bhN = bhP[cr + 32];
  float hold[4][4];
#pragma unroll
  for (int m2 = 0; m2 < 4; ++m2)
#pragma unroll
    for (int r = 0; r < 4; ++r) {
      int b = b0 + 16 * m2 + 4 * q + r;
      hold[m2][r] = hfPrev[(size_t)b * kH + j];  // block-local, cached
    }
#pragma unroll
  for (int m2 = 0; m2 < 4; ++m2)
#pragma unroll
    for (int r = 0; r < 4; ++r) {
      int b = b0 + 16 * m2 + 4 * q + r;
      float rg = 1.f / (1.f + __expf(-(aR[m2][r] * kInvSS + bR)));
      float zg = 1.f / (1.f + __expf(-(aZ[m2][r] * kInvSS + bZ)));
      float np = (aNi[m2][r] * kInvSS + biN) + rg * (aNh[m2][r] * kInvSS + bhN);
      float nh = 2.f / (1.f + __expf(-2.f * np)) - 1.f;   // tanh
      float hnew = (1.f - zg) * nh + zg * hold[m2][r];
      hfOut[(size_t)b * kH + j] = hnew;                   // local fp32, cached
      stv_u8(&hbOut[(size_t)b * kH + j], f2e4m3(hnew * kScale));  // cross-block fp8, MALL
    }
}

// ---------------- E stage: logits + log_softmax + gather (16 rows/block) ----------------
// R13 form; A-panel staged at the union base (first 16KB), batched single issue.
__device__ void do_E(SMem& sm, const u8* __restrict__ h3b, const u8* __restrict__ wo,
                     const float* __restrict__ b_out, const int* __restrict__ target,
                     float* __restrict__ lp, int u, int tile)
{
  const int b0 = tile * 16;
  const int t = threadIdx.x, lane = t & 63, wv = t >> 6;
  const int li = lane & 15, q = lane >> 4;
  u8* pan = (u8*)&sm;                        // 16KB A-panel at union base

  {
    const int row = t & 15, th = t >> 4;
    const int q2 = th & 3, kc = th >> 2;
    const u8* srcb = h3b + (size_t)(b0 + row) * kH + q2 * 8;
    uint64_t s0 = ldv_u64(srcb + (0 * 4 + kc) * 32);
    uint64_t s1 = ldv_u64(srcb + (1 * 4 + kc) * 32);
    uint64_t s2 = ldv_u64(srcb + (2 * 4 + kc) * 32);
    uint64_t s3 = ldv_u64(srcb + (3 * 4 + kc) * 32);
    uint64_t s4 = ldv_u64(srcb + (4 * 4 + kc) * 32);
    uint64_t s5 = ldv_u64(srcb + (5 * 4 + kc) * 32);
    uint64_t s6 = ldv_u64(srcb + (6 * 4 + kc) * 32);
    uint64_t s7 = ldv_u64(srcb + (7 * 4 + kc) * 32);
    u8* db = pan + kc * 512 + row * 32 + q2 * 8;   // tile stride 4*512=2048
    *(uint64_t*)(db + 0 * 2048) = s0;
    *(uint64_t*)(db + 1 * 2048) = s1;
    *(uint64_t*)(db + 2 * 2048) = s2;
    *(uint64_t*)(db + 3 * 2048) = s3;
    *(uint64_t*)(db + 4 * 2048) = s4;
    *(uint64_t*)(db + 5 * 2048) = s5;
    *(uint64_t*)(db + 6 * 2048) = s6;
    *(uint64_t*)(db + 7 * 2048) = s7;
  }
  __syncthreads();   // A-panel in LDS

  f4v acc[6];
#pragma unroll
  for (int f = 0; f < 6; ++f) acc[f] = f4v{0.f, 0.f, 0.f, 0.f};

  const u8* wp = wo + (size_t)(96 * wv + li) * kH + q * 8;   // f stride = 16*kH
  const u8* al = pan + li * 32 + q * 8;                      // + (k0/32)*512

  uint64_t bE[6], bO[6];
#pragma unroll
  for (int f = 0; f < 6; ++f) bE[f] = *(const uint64_t*)(wp + (size_t)16 * f * kH);
#pragma unroll
  for (int f = 0; f < 6; ++f) bO[f] = *(const uint64_t*)(wp + (size_t)16 * f * kH + 32);

#pragma unroll 1
  for (int k0 = 0; k0 < kH; k0 += 64) {
    uint64_t bT[6];
    if (k0 + 64 < kH) {
#pragma unroll
      for (int f = 0; f < 6; ++f) bT[f] = *(const uint64_t*)(wp + (size_t)16 * f * kH + k0 + 64);
    }
    const uint64_t aE = *(const uint64_t*)(al + (k0 >> 5) * 512);
#pragma unroll
    for (int f = 0; f < 6; ++f)
      acc[f] = __builtin_amdgcn_mfma_f32_16x16x32_fp8_fp8((long)aE, (long)bE[f], acc[f], 0, 0, 0);
    if (k0 + 64 < kH) {
#pragma unroll
      for (int f = 0; f < 6; ++f) bE[f] = bT[f];
    }
    if (k0 + 96 < kH) {
#pragma unroll
      for (int f = 0; f < 6; ++f) bT[f] = *(const uint64_t*)(wp + (size_t)16 * f * kH + k0 + 96);
    }
    const uint64_t aO = *(const uint64_t*)(al + ((k0 + 32) >> 5) * 512);
#pragma unroll
    for (int f = 0; f < 6; ++f)
      acc[f] = __builtin_amdgcn_mfma_f32_16x16x32_fp8_fp8((long)aO, (long)bO[f], acc[f], 0, 0, 0);
    if (k0 + 96 < kH) {
#pragma unroll
      for (int f = 0; f < 6; ++f) bO[f] = bT[f];
    }
  }
  __syncthreads();   // done reading A-panel (logits region aliases it)
#pragma unroll
  for (int f = 0; f < 6; ++f) {
    int n = 96 * wv + 16 * f + li;
    if (n < kV) {
      float bo = b_out[n];
#pragma unroll
      for (int r = 0; r < 4; ++r)
        sm.logits[(4 * q + r) * 400 + n] = acc[f][r] * kInvSS + bo;
    }
  }
  __syncthreads();
  int m = 4 * wv + q;
  int b = b0 + m;
  float mx = -1e30f;
  for (int cc = li; cc < kV; cc += 16) mx = fmaxf(mx, sm.logits[m * 400 + cc]);
#pragma unroll
  for (int d = 1; d < 16; d <<= 1) mx = fmaxf(mx, __shfl_xor(mx, d, 16));
  float se = 0.f;
  for (int cc = li; cc < kV; cc += 16) se += __expf(sm.logits[m * 400 + cc] - mx);
#pragma unroll
  for (int d = 1; d < 16; d <<= 1) se += __shfl_xor(se, d, 16);
  int tgt = target[b * kT + u];
  float logp = sm.logits[m * 400 + tgt] - mx - __logf(se);
  if (li == 0) lp[b] += logp;
  __syncthreads();   // logits LDS reused next step
}

// ---------------- main persistent kernel ----------------
__global__ __launch_bounds__(256, 1) void rnn_main(Params P)
{
  __shared__ SMem sm;
  const int bid = blockIdx.x;
  const int bos = P.bosp[0];
  const size_t HS = (size_t)kB * kH;

  // 64 blocks/layer = 4 mt x 16 jt; mt-quad sharing a weight panel sits 16 bids
  // apart (same XCD under bid%8 round-robin -> L2 absorbs the 4x weight re-read).
  const int local = bid & 63;
  const int mt = (local >> 4) & 3;
  const int jt = local & 15;

  for (int s = 0; s < kT + 3; ++s) {
    if (bid < 64) {                        // layer 1, u = s
      int u = s;
      if (u < kT)
        do_L<kE, true>(sm, P.embb,
                       P.h1b + (size_t)((u - 1) & 1) * HS, P.h1f + (size_t)((u - 1) & 1) * HS,
                       P.w1i, P.w1h, P.bi1, P.bh1,
                       P.h1f + (size_t)(u & 1) * HS, P.h1b + (size_t)(u & 1) * HS,
                       P.target, bos, u, mt, jt);
    } else if (bid < 128) {                // layer 2, u = s-1
      int u = s - 1;
      if (u >= 0 && u < kT)
        do_L<kH, false>(sm, P.h1b + (size_t)(u & 1) * HS,
                        P.h2b + (size_t)((u - 1) & 1) * HS, P.h2f + (size_t)((u - 1) & 1) * HS,
                        P.w2i, P.w2h, P.bi2, P.bh2,
                        P.h2f + (size_t)(u & 1) * HS, P.h2b + (size_t)(u & 1) * HS,
                        P.target, bos, u, mt, jt);
    } else if (bid < 192) {                // layer 3, u = s-2
      int u = s - 2;
      if (u >= 0 && u < kT)
        do_L<kH, false>(sm, P.h2b + (size_t)(u & 1) * HS,
                        P.h3b + (size_t)((u - 1) & 1) * HS, P.h3f + (size_t)((u - 1) & 1) * HS,
                        P.w3i, P.w3h, P.bi3, P.bh3,
                        P.h3f + (size_t)(u & 1) * HS, P.h3b + (size_t)(u & 1) * HS,
                        P.target, bos, u, mt, jt);
    } else {                               // E, u = s-3
      int u = s - 3;
      if (u >= 0 && u < kT)
        do_E(sm, P.h3b + (size_t)(u & 1) * HS, P.wout, P.b_out, P.target, P.lp, u, bid - 192);
    }
    gbar(P.acnt, P.gflag, (unsigned)s);
  }
}

// ---------------- conversion / init kernels (fp8 x32) ----------------
__global__ void k_conv_w(const float* __restrict__ w, u8* __restrict__ wp, int K, int logK) {
  int idx = blockIdx.x * 256 + threadIdx.x;
  if (idx >= kNG * K) return;
  int n = idx >> logK, k = idx & (K - 1);
  wp[(size_t)permn(n) * K + k] = f2e4m3(w[idx] * kScale);
}
__global__ void k_conv_b(const float* __restrict__ b, float* __restrict__ bp) {
  int idx = blockIdx.x * 256 + threadIdx.x;
  if (idx < kNG) bp[permn(idx)] = b[idx];
}
__global__ void k_conv_wout(const float* __restrict__ w, u8* __restrict__ wp) {
  int idx = blockIdx.x * 256 + threadIdx.x;
  if (idx >= 384 * kH) return;
  int n = idx >> 10, k = idx & 1023;
  wp[idx] = (n < kV) ? f2e4m3(w[(size_t)n * kH + k] * kScale) : (u8)0;
}
__global__ void k_conv_emb(const float* __restrict__ e, u8* __restrict__ ep) {
  int idx = blockIdx.x * 256 + threadIdx.x;
  if (idx < kV * kE) ep[idx] = f2e4m3(e[idx] * kScale);
}

extern "C" void kernel_launch(void* const* d_in, const int* in_sizes, int n_in,
                              void* d_out, int out_size, void* d_ws, size_t ws_size,
                              hipStream_t stream)
{
  const int*   target = (const int*)d_in[0];
  const int*   bosp   = (const int*)d_in[1];
  const float* emb    = (const float*)d_in[2];
  const float* w_ih1  = (const float*)d_in[3];
  const float* w_hh1  = (const float*)d_in[4];
  const float* b_ih1  = (const float*)d_in[5];
  const float* b_hh1  = (const float*)d_in[6];
  const float* w_ih2  = (const float*)d_in[7];
  const float* w_hh2  = (const float*)d_in[8];
  const float* b_ih2  = (const float*)d_in[9];
  const float* b_hh2  = (const float*)d_in[10];
  const float* w_ih3  = (const float*)d_in[11];
  const float* w_hh3  = (const float*)d_in[12];
  const float* b_ih3  = (const float*)d_in[13];
  const float* b_hh3  = (const float*)d_in[14];
  const float* w_out  = (const float*)d_in[15];
  const float* b_out  = (const float*)d_in[16];

  char* ws = (char*)d_ws;
  size_t off = 0;
  auto alloc = [&](size_t bytes) -> void* {
    void* p = ws + off;
    off = (off + bytes + 511) & ~(size_t)511;
    return p;
  };
  u8* w1i = (u8*)alloc((size_t)kNG * kE);
  u8* w1h = (u8*)alloc((size_t)kNG * kH);
  u8* w2i = (u8*)alloc((size_t)kNG * kH);
  u8* w2h = (u8*)alloc((size_t)kNG * kH);
  u8* w3i = (u8*)alloc((size_t)kNG * kH);
  u8* w3h = (u8*)alloc((size_t)kNG * kH);
  u8* wo  = (u8*)alloc((size_t)384 * kH);
  u8* eb  = (u8*)alloc((size_t)kV * kE);
  float* bi1 = (float*)alloc(kNG * 4);
  float* bh1 = (float*)alloc(kNG * 4);
  float* bi2 = (float*)alloc(kNG * 4);
  float* bh2 = (float*)alloc(kNG * 4);
  float* bi3 = (float*)alloc(kNG * 4);
  float* bh3 = (float*)alloc(kNG * 4);
  float* h1f = (float*)alloc((size_t)2 * kB * kH * 4);
  float* h2f = (float*)alloc((size_t)2 * kB * kH * 4);
  float* h3f = (float*)alloc((size_t)2 * kB * kH * 4);
  u8* h1b = (u8*)alloc((size_t)2 * kB * kH);
  u8* h2b = (u8*)alloc((size_t)2 * kB * kH);
  u8* h3b = (u8*)alloc((size_t)2 * kB * kH);
  unsigned* bar = (unsigned*)alloc(4096);
  (void)ws_size; (void)in_sizes; (void)n_in; (void)out_size;

  k_conv_w<<<(kNG * kE + 255) / 256, 256, 0, stream>>>(w_ih1, w1i, kE, 9);
  k_conv_w<<<(kNG * kH + 255) / 256, 256, 0, stream>>>(w_hh1, w1h, kH, 10);
  k_conv_w<<<(kNG * kH + 255) / 256, 256, 0, stream>>>(w_ih2, w2i, kH, 10);
  k_conv_w<<<(kNG * kH + 255) / 256, 256, 0, stream>>>(w_hh2, w2h, kH, 10);
  k_conv_w<<<(kNG * kH + 255) / 256, 256, 0, stream>>>(w_ih3, w3i, kH, 10);
  k_conv_w<<<(kNG * kH + 255) / 256, 256, 0, stream>>>(w_hh3, w3h, kH, 10);
  k_conv_b<<<(kNG + 255) / 256, 256, 0, stream>>>(b_ih1, bi1);
  k_conv_b<<<(kNG + 255) / 256, 256, 0, stream>>>(b_hh1, bh1);
  k_conv_b<<<(kNG + 255) / 256, 256, 0, stream>>>(b_ih2, bi2);
  k_conv_b<<<(kNG + 255) / 256, 256, 0, stream>>>(b_hh2, bh2);
  k_conv_b<<<(kNG + 255) / 256, 256, 0, stream>>>(b_ih3, bi3);
  k_conv_b<<<(kNG + 255) / 256, 256, 0, stream>>>(b_hh3, bh3);
  k_conv_wout<<<(384 * kH + 255) / 256, 256, 0, stream>>>(w_out, wo);
  k_conv_emb<<<(kV * kE + 255) / 256, 256, 0, stream>>>(emb, eb);

  hipMemsetAsync(h1f, 0, (size_t)3 * 2 * kB * kH * 4, stream);  // h1f,h2f,h3f contiguous
  hipMemsetAsync(h1b, 0, (size_t)3 * 2 * kB * kH, stream);      // h1b,h2b,h3b contiguous
  hipMemsetAsync(bar, 0, 4096, stream);
  hipMemsetAsync(d_out, 0, (size_t)kB * 4, stream);

  Params P;
  P.target = target; P.bosp = bosp; P.b_out = b_out;
  P.w1i = w1i; P.w1h = w1h; P.w2i = w2i; P.w2h = w2h; P.w3i = w3i; P.w3h = w3h;
  P.wout = wo; P.embb = eb;
  P.bi1 = bi1; P.bh1 = bh1; P.bi2 = bi2; P.bh2 = bh2; P.bi3 = bi3; P.bh3 = bh3;
  P.h1f = h1f; P.h2f = h2f; P.h3f = h3f;
  P.h1b = h1b; P.h2b = h2b; P.h3b = h3b;
  P.lp = (float*)d_out;
  P.acnt = bar; P.gflag = bar + 512;

  rnn_main<<<dim3(NB), dim3(256), 0, stream>>>(P);
}